// Round 2
// baseline (30667.905 us; speedup 1.0000x reference)
//
#include <hip/hip_runtime.h>
#include <hip/hip_cooperative_groups.h>
#include <math.h>

namespace cg = cooperative_groups;

#define NXF 512
#define NPTS (NXF * NXF)   // 262144
#define NB 4
#define NT 256
#define NM 256

// ---------------------------------------------------------------------------
// Persistent cooperative kernel: all 256 time steps in ONE launch.
// Field layout: batch-innermost float4 — buf[idx] = {p[b=0..3] at idx}.
// Per-thread persistent state (registers): pprev (p0 role), vel2, meas id/src.
// Per step: 9 float4 stencil loads from cur, 1 float4 store to nxt,
// grid.sync(). p0 / vel2 / meas mask never touch global memory in the loop.
// ---------------------------------------------------------------------------
__global__ __launch_bounds__(256, 4) void wave_all_kernel(
    const float* __restrict__ x,       // (4,1,256,256)
    const float* __restrict__ se,      // (64,)
    float* __restrict__ out,           // (4,1,256,256) = [b][mid][t]
    float4* __restrict__ bufA,         // NPTS float4
    float4* __restrict__ bufB,         // NPTS float4
    const int* __restrict__ sIdx,      // 256 sorted meas idx
    const int* __restrict__ sMid,      // matching mid
    const float* __restrict__ srcTab)  // 256 source wavelet values
{
    cg::grid_group grid = cg::this_grid();
    int idx = blockIdx.x * 256 + threadIdx.x;   // 0..262143, covers 512x512
    int i = idx >> 9;
    int j = idx & 511;
    int row = i << 9;

    // Periodic stencil offsets (float4 units) — fixed for the whole run.
    int o_im2 = (((i - 2) & 511) << 9) | j;
    int o_im1 = (((i - 1) & 511) << 9) | j;
    int o_ip1 = (((i + 1) & 511) << 9) | j;
    int o_ip2 = (((i + 2) & 511) << 9) | j;
    int o_jm2 = row | ((j - 2) & 511);
    int o_jm1 = row | ((j - 1) & 511);
    int o_jp1 = row | ((j + 1) & 511);
    int o_jp2 = row | ((j + 2) & 511);
    int o_c   = row | j;

    // vel2 in registers, computed from x (padded layout: 55-frame=1e-6,
    // bg=1.5 ring, x in [128,384)^2).
    float v2[NB];
#pragma unroll
    for (int b = 0; b < NB; ++b) {
        float v;
        if (i < 55 || i >= 457 || j < 55 || j >= 457) {
            v = 1e-6f;
        } else if (i >= 128 && i < 384 && j >= 128 && j < 384) {
            v = x[(b << 16) + ((i - 128) << 8) + (j - 128)];
        } else {
            v = 1.5f;
        }
        float a = (2e-05f * v) / 1e-04f;
        v2[b] = a * a;
    }

    // Resolve measurement id once: binary search sorted 256-entry table.
    int mid = -1;
    {
        int lo = 0, hi = NM - 1;
        while (lo <= hi) {
            int m = (lo + hi) >> 1;
            int vI = sIdx[m];
            if (vI == idx) { mid = sMid[m]; break; }
            if (vI < idx) lo = m + 1; else hi = m - 1;
        }
    }
    const bool isMeas  = (mid >= 0);
    const bool isTrans = isMeas && ((mid & 3) == 0);
    float srcw = 0.0f;
    if (isTrans) srcw = 0.09000000000000002f * se[mid >> 2];  // SRC_COEF * se

    // Zero the initial p1 buffer; p0 lives in registers (starts 0).
    float pprev[NB] = {0.0f, 0.0f, 0.0f, 0.0f};
    bufA[idx] = make_float4(0.0f, 0.0f, 0.0f, 0.0f);

    float4* cur = bufA;
    float4* nxt = bufB;
    grid.sync();

    for (int t = 0; t < NT; ++t) {
        float4 c4   = cur[o_c];
        float4 im2  = cur[o_im2];
        float4 im1  = cur[o_im1];
        float4 ip1  = cur[o_ip1];
        float4 ip2  = cur[o_ip2];
        float4 jm2  = cur[o_jm2];
        float4 jm1  = cur[o_jm1];
        float4 jp1  = cur[o_jp1];
        float4 jp2  = cur[o_jp2];

        float s = 0.0f;
        if (isTrans) s = srcw * srcTab[t];

        float c[NB]  = {c4.x, c4.y, c4.z, c4.w};
        float a2[NB] = {im2.x, im2.y, im2.z, im2.w};
        float a1[NB] = {im1.x, im1.y, im1.z, im1.w};
        float b1[NB] = {ip1.x, ip1.y, ip1.z, ip1.w};
        float b2[NB] = {ip2.x, ip2.y, ip2.z, ip2.w};
        float l2[NB] = {jm2.x, jm2.y, jm2.z, jm2.w};
        float l1[NB] = {jm1.x, jm1.y, jm1.z, jm1.w};
        float r1[NB] = {jp1.x, jp1.y, jp1.z, jp1.w};
        float r2[NB] = {jp2.x, jp2.y, jp2.z, jp2.w};

        float pn[NB];
#pragma unroll
        for (int b = 0; b < NB; ++b) {
            float nab_x = (-a2[b] + 16.0f * a1[b] - 30.0f * c[b]
                           + 16.0f * b1[b] - b2[b]) * (1.0f / 12.0f);
            float nab_y = (-l2[b] + 16.0f * l1[b] - 30.0f * c[b]
                           + 16.0f * r1[b] - r2[b]) * (1.0f / 12.0f);
            float p = 2.0f * c[b] - pprev[b] + v2[b] * (nab_x + nab_y);
            if (isTrans) p += s;
            pn[b] = p;
            pprev[b] = c[b];
        }

        if (isMeas) {
#pragma unroll
            for (int b = 0; b < NB; ++b)
                out[(b << 16) | (mid << 8) | t] = pn[b];
        }

        nxt[idx] = make_float4(pn[0], pn[1], pn[2], pn[3]);

        float4* tmp = cur; cur = nxt; nxt = tmp;
        grid.sync();
    }
}

// ---------------------------------------------------------------------------
// Host launch
// ---------------------------------------------------------------------------
extern "C" void kernel_launch(void* const* d_in, const int* in_sizes, int n_in,
                              void* d_out, int out_size, void* d_ws, size_t ws_size,
                              hipStream_t stream) {
    const float* x  = (const float*)d_in[0];
    const float* se = (const float*)d_in[1];
    float* out = (float*)d_out;

    char* ws = (char*)d_ws;
    const size_t FIELD_BYTES = (size_t)NPTS * sizeof(float4);  // 4 MB
    float4* bufA = (float4*)(ws);
    float4* bufB = (float4*)(ws + FIELD_BYTES);
    int*    dIdx = (int*)   (ws + 2 * FIELD_BYTES);
    int*    dMid = (int*)   (ws + 2 * FIELD_BYTES + NM * 4);
    float*  dSrc = (float*) (ws + 2 * FIELD_BYTES + 2 * NM * 4);

    // Host tables: meas indices via double trig (bit-identical to numpy f64),
    // sorted by idx for device binary search; fp32 wavelet like numpy f32.
    static int   h_idx[NM];
    static int   h_mid[NM];
    static float h_src[NT];
    for (int m = 0; m < NM; ++m) {
        double theta = (2.0 * M_PI * (double)m) / 256.0;
        int mx = (int)(256.0 + 200.0 * cos(theta));
        int my = (int)(256.0 + 200.0 * sin(theta));
        h_idx[m] = mx * NXF + my;
        h_mid[m] = m;
    }
    // insertion sort by idx
    for (int a = 1; a < NM; ++a) {
        int ki = h_idx[a], km = h_mid[a];
        int bpos = a - 1;
        while (bpos >= 0 && h_idx[bpos] > ki) {
            h_idx[bpos + 1] = h_idx[bpos];
            h_mid[bpos + 1] = h_mid[bpos];
            --bpos;
        }
        h_idx[bpos + 1] = ki;
        h_mid[bpos + 1] = km;
    }
    for (int t = 0; t < NT; ++t) {
        float tj  = (float)t * 2e-05f;
        float arg = (float)(2.0 * M_PI * 500.0) * tj;
        float d   = tj - 0.002f;
        float e   = -(d * d) / (float)(2.0 * 0.001 * 0.001);
        h_src[t]  = sinf(arg) * expf(e);
    }
    hipMemcpyAsync(dIdx, h_idx, sizeof(h_idx), hipMemcpyHostToDevice, stream);
    hipMemcpyAsync(dMid, h_mid, sizeof(h_mid), hipMemcpyHostToDevice, stream);
    hipMemcpyAsync(dSrc, h_src, sizeof(h_src), hipMemcpyHostToDevice, stream);

    void* args[] = {(void*)&x, (void*)&se, (void*)&out, (void*)&bufA, (void*)&bufB,
                    (void*)&dIdx, (void*)&dMid, (void*)&dSrc};
    hipLaunchCooperativeKernel((void*)wave_all_kernel, dim3(NPTS / 256), dim3(256),
                               args, 0, stream);
}

// Round 3
// 1103.932 us; speedup vs baseline: 27.7806x; 27.7806x over previous
//
#include <hip/hip_runtime.h>
#include <math.h>

#define NXG 512
#define NPTS (NXG * NXG)        // 262144 per batch
#define NB 4
#define NT 256
#define NM 256
#define K 8                     // steps per chunk kernel
#define NCH (NT / K)            // 32 chunks
#define WA 64                   // LDS array dim (32 tile + 2*16 halo)
#define STR 68                  // padded LDS row stride (floats) -> conflict-free b128
#define TSLOTS 64               // per-tile meas-table slots

// ---------------------------------------------------------------------------
// zero first 8MB of ws (chunk-0 input field pair)
// ---------------------------------------------------------------------------
__global__ __launch_bounds__(256) void zero_kernel(float4* __restrict__ p) {
    p[blockIdx.x * 256 + threadIdx.x] = make_float4(0.f, 0.f, 0.f, 0.f);
}

// ---------------------------------------------------------------------------
// One chunk = K=8 time steps, trapezoidal temporal blocking.
// Per block: one (32x32 tile, batch). LDS holds one 64x64 halo-extended field
// (stride 68). Each thread owns a 4x4 cell block: cur/prev/vel2 in REGISTERS.
// Validity region shrinks [2+2s, 64-2-2s) per step; garbage outside the
// region is never read (reads at step s stop exactly at region(s-1) edge).
// ---------------------------------------------------------------------------
__global__ __launch_bounds__(256, 4) void chunk_kernel(
    const float* __restrict__ x,       // (4,1,256,256)
    const float* __restrict__ se,      // (64,)
    float* __restrict__ out,           // (4,1,256,256) = [b][m][t]
    const float* __restrict__ gA,      // f_{n0}   (full domain, all batches)
    const float* __restrict__ gB,      // f_{n0-1}
    float* __restrict__ wA,            // f_{n0+K}
    float* __restrict__ wB,            // f_{n0+K-1}
    const int* __restrict__ tileTab,   // 256 tiles x 64 slots, packed d<<14|e<<8|m, -1 end
    const float* __restrict__ srcT,    // 256 wavelet values
    int n0)
{
    __shared__ __align__(16) float A[WA * STR];

    const int tid = threadIdx.x;
    const int blk = blockIdx.x;
    const int b   = blk >> 8;          // batch
    const int tb  = blk & 255;         // tile id
    const int gi0 = (tb >> 4) << 5;    // tile origin
    const int gj0 = (tb & 15) << 5;
    const int bi0 = gi0 - 16;          // array(0,0) global coords
    const int bj0 = gj0 - 16;

    const int rb = tid >> 4;           // 0..15 row-block
    const int cb = tid & 15;           // 0..15 col-block
    const int r0 = rb << 2;            // own rows r0..r0+3 (array coords)
    const int c0 = cb << 2;            // own cols c0..c0+3

    // ---- fill LDS with f_{n0} (periodic wrap) ----
    const float* gAb = gA + (b << 18);
    for (int l = tid; l < WA * WA; l += 256) {
        int li = l >> 6, lj = l & 63;
        int gi = (bi0 + li) & 511, gj = (bj0 + lj) & 511;
        A[li * STR + lj] = gAb[(gi << 9) | gj];
    }

    // ---- per-thread register state: prev field, vel^2 ----
    float curR[4][4], prvR[4][4], v2R[4][4];
    const float* gBb = gB + (b << 18);
#pragma unroll
    for (int r = 0; r < 4; ++r) {
        int gi = (bi0 + r0 + r) & 511;
#pragma unroll
        for (int c = 0; c < 4; ++c) {
            int gj = (bj0 + c0 + c) & 511;
            prvR[r][c] = gBb[(gi << 9) | gj];
            float v;
            if (gi < 55 || gi >= 457 || gj < 55 || gj >= 457) v = 1e-6f;
            else if (gi >= 128 && gi < 384 && gj >= 128 && gj < 384)
                v = x[(b << 16) | ((gi - 128) << 8) | (gj - 128)];
            else v = 1.5f;
            float a = (2e-05f * v) / 1e-04f;
            v2R[r][c] = a * a;
        }
    }

    // ---- resolve injection / measurement ownership from per-tile table ----
    int injCell = -1;  float injVal = 0.0f;
    int m1Cell = -1, m1Addr = 0, m2Cell = -1, m2Addr = 0;
    {
        const int* tt = tileTab + (tb << 6);
        for (int slot = 0; slot < TSLOTS; ++slot) {
            int pk = tt[slot];
            if (pk < 0) break;
            int d = pk >> 14, e = (pk >> 8) & 63, m = pk & 255;
            int lr = d - r0, lc = e - c0;
            if (lr < 0 || lr >= 4 || lc < 0 || lc >= 4) continue;
            int cell = (lr << 2) | lc;
            if ((m & 3) == 0) { injCell = cell; injVal = 0.09f * se[m >> 2]; }
            if (d >= 16 && d < 48 && e >= 16 && e < 48) {
                int addr = (b << 16) | (m << 8);
                if (m1Cell < 0) { m1Cell = cell; m1Addr = addr; }
                else            { m2Cell = cell; m2Addr = addr; }
            }
        }
    }

    __syncthreads();

    // own cur cells from LDS
#pragma unroll
    for (int r = 0; r < 4; ++r) {
        float4 t = *(const float4*)&A[(r0 + r) * STR + c0];
        curR[r][0] = t.x; curR[r][1] = t.y; curR[r][2] = t.z; curR[r][3] = t.w;
    }

    for (int s = 0; s < K; ++s) {
        const int lo = 2 + 2 * s;
        const int hi = WA - lo;
        const int n  = n0 + s;
        const float sv = srcT[n];

        bool rowAct[4];
#pragma unroll
        for (int r = 0; r < 4; ++r) {
            int ar = r0 + r;
            rowAct[r] = (ar >= lo) && (ar < hi);
        }

        float newR[4][4];
        // x-direction halo rows (only rows outside own 4x4 need LDS)
        float hxa[4], hxb[4], hxc[4], hxd[4];
        if (rowAct[0]) {
            float4 t = *(const float4*)&A[(r0 - 2) * STR + c0];
            hxa[0]=t.x; hxa[1]=t.y; hxa[2]=t.z; hxa[3]=t.w;
        }
        if (rowAct[0] || rowAct[1]) {
            float4 t = *(const float4*)&A[(r0 - 1) * STR + c0];
            hxb[0]=t.x; hxb[1]=t.y; hxb[2]=t.z; hxb[3]=t.w;
        }
        if (rowAct[2] || rowAct[3]) {
            float4 t = *(const float4*)&A[(r0 + 4) * STR + c0];
            hxc[0]=t.x; hxc[1]=t.y; hxc[2]=t.z; hxc[3]=t.w;
        }
        if (rowAct[3]) {
            float4 t = *(const float4*)&A[(r0 + 5) * STR + c0];
            hxd[0]=t.x; hxd[1]=t.y; hxd[2]=t.z; hxd[3]=t.w;
        }
        // y-direction halo (2 cols each side, from neighbor col-blocks)
        float yl[4][2], yr[4][2];
#pragma unroll
        for (int r = 0; r < 4; ++r) {
            if (rowAct[r]) {
                int ar = r0 + r;
                float2 t1 = *(const float2*)&A[ar * STR + c0 - 2];
                float2 t2 = *(const float2*)&A[ar * STR + c0 + 4];
                yl[r][0] = t1.x; yl[r][1] = t1.y;
                yr[r][0] = t2.x; yr[r][1] = t2.y;
            }
        }

#pragma unroll
        for (int r = 0; r < 4; ++r) {
            if (!rowAct[r]) continue;
            float xm2_[4], xm1_[4], xp1_[4], xp2_[4];
#pragma unroll
            for (int c = 0; c < 4; ++c) {
                xm2_[c] = (r == 0) ? hxa[c] : (r == 1) ? hxb[c]
                                            : curR[(r >= 2) ? r - 2 : 0][c];
                xm1_[c] = (r == 0) ? hxb[c] : curR[(r >= 1) ? r - 1 : 0][c];
                xp1_[c] = (r < 3) ? curR[(r < 3) ? r + 1 : 3][c] : hxc[c];
                xp2_[c] = (r < 2) ? curR[(r < 2) ? r + 2 : 3][c]
                                  : ((r == 2) ? hxc[c] : hxd[c]);
            }
            float y[8] = {yl[r][0], yl[r][1],
                          curR[r][0], curR[r][1], curR[r][2], curR[r][3],
                          yr[r][0], yr[r][1]};
#pragma unroll
            for (int c = 0; c < 4; ++c) {
                float cc = curR[r][c];
                float nx = (-xm2_[c] + 16.0f * xm1_[c] - 30.0f * cc
                            + 16.0f * xp1_[c] - xp2_[c]) * (1.0f / 12.0f);
                float ny = (-y[c] + 16.0f * y[c + 1] - 30.0f * y[c + 2]
                            + 16.0f * y[c + 3] - y[c + 4]) * (1.0f / 12.0f);
                float p = 2.0f * cc - prvR[r][c] + v2R[r][c] * (nx + ny);
                int cell = (r << 2) | c;
                if (cell == injCell) p += injVal * sv;
                if (cell == m1Cell) out[m1Addr | n] = p;
                if (cell == m2Cell) out[m2Addr | n] = p;
                newR[r][c] = p;
            }
        }

        __syncthreads();   // all LDS reads of step s done

#pragma unroll
        for (int r = 0; r < 4; ++r) {
            if (!rowAct[r]) continue;
            *(float4*)&A[(r0 + r) * STR + c0] =
                make_float4(newR[r][0], newR[r][1], newR[r][2], newR[r][3]);
#pragma unroll
            for (int c = 0; c < 4; ++c) {
                prvR[r][c] = curR[r][c];
                curR[r][c] = newR[r][c];
            }
        }

        // last two fields of the chunk -> global (interior cells only)
        if (s >= K - 2 && r0 >= 16 && r0 < 48 && c0 >= 16 && c0 < 48) {
            float* dst = (s == K - 2) ? wB : wA;
            int gj = gj0 + (c0 - 16);
#pragma unroll
            for (int r = 0; r < 4; ++r) {
                int gi = gi0 + (r0 - 16) + r;
                *(float4*)&dst[(b << 18) | (gi << 9) | gj] =
                    make_float4(curR[r][0], curR[r][1], curR[r][2], curR[r][3]);
            }
        }

        __syncthreads();   // LDS writes visible before next step's reads
    }
}

// ---------------------------------------------------------------------------
// Host launch
// ---------------------------------------------------------------------------
extern "C" void kernel_launch(void* const* d_in, const int* in_sizes, int n_in,
                              void* d_out, int out_size, void* d_ws, size_t ws_size,
                              hipStream_t stream) {
    const float* x  = (const float*)d_in[0];
    const float* se = (const float*)d_in[1];
    float* out = (float*)d_out;

    float* ws = (float*)d_ws;
    const int FSZ = NB * NPTS;                 // 1048576 floats = 4MB per field
    float* f[4] = {ws, ws + FSZ, ws + 2 * FSZ, ws + 3 * FSZ};  // f0A,f0B,f1A,f1B
    int*   dTab = (int*)(ws + 4 * FSZ);
    float* dSrc = (float*)(ws + 4 * FSZ + 256 * TSLOTS);

    // ---- host tables ----
    static int   h_tab[256 * TSLOTS];
    static float h_src[NT];
    static int   h_mx[NM], h_my[NM];
    for (int m = 0; m < NM; ++m) {
        double theta = (2.0 * M_PI * (double)m) / 256.0;
        h_mx[m] = (int)(256.0 + 200.0 * cos(theta));
        h_my[m] = (int)(256.0 + 200.0 * sin(theta));
    }
    for (int tile = 0; tile < 256; ++tile) {
        int bi0 = ((tile >> 4) << 5) - 16;
        int bj0 = ((tile & 15) << 5) - 16;
        int cnt = 0;
        for (int m = 0; m < NM; ++m) {
            int d = (h_mx[m] - bi0) & 511;
            int e = (h_my[m] - bj0) & 511;
            if (d < WA && e < WA && cnt < TSLOTS - 1)
                h_tab[tile * TSLOTS + cnt++] = (d << 14) | (e << 8) | m;
        }
        for (; cnt < TSLOTS; ++cnt) h_tab[tile * TSLOTS + cnt] = -1;
    }
    for (int t = 0; t < NT; ++t) {
        float tj  = (float)t * 2e-05f;
        float arg = (float)(2.0 * M_PI * 500.0) * tj;
        float d   = tj - 0.002f;
        float e   = -(d * d) / (float)(2.0 * 0.001 * 0.001);
        h_src[t]  = sinf(arg) * expf(e);
    }
    hipMemcpyAsync(dTab, h_tab, sizeof(h_tab), hipMemcpyHostToDevice, stream);
    hipMemcpyAsync(dSrc, h_src, sizeof(h_src), hipMemcpyHostToDevice, stream);

    // zero chunk-0 input pair (f0A, f0B are contiguous: 8MB = 524288 float4)
    zero_kernel<<<2048, 256, 0, stream>>>((float4*)ws);

    for (int c = 0; c < NCH; ++c) {
        int p = c & 1, q = p ^ 1;
        chunk_kernel<<<NB * 256, 256, 0, stream>>>(
            x, se, out,
            f[2 * p], f[2 * p + 1],     // read  pair: f_{8c}, f_{8c-1}
            f[2 * q], f[2 * q + 1],     // write pair: f_{8c+8}, f_{8c+7}
            dTab, dSrc, c * K);
    }
}

// Round 5
// 981.269 us; speedup vs baseline: 31.2533x; 1.1250x over previous
//
#include <hip/hip_runtime.h>
#include <math.h>

#define NXG 512
#define NPTS (NXG * NXG)
#define NB 4
#define NT 256
#define NM 256
#define K 8                 // steps per chunk
#define NCH (NT / K)        // 32 chunks
#define TILE 64             // interior tile written back per chunk
#define WA 96               // halo-extended array (TILE + 2*2*K)
#define STR 100             // LDS row stride
#define NTHR 576            // 24x24 thread grid, each owns 4x4 cells
#define NTILES 64           // 8x8 tiles cover 512x512
#define TSLOTS 64

// ---------------------------------------------------------------------------
__global__ __launch_bounds__(256) void zero_kernel(float4* __restrict__ p) {
    p[blockIdx.x * 256 + threadIdx.x] = make_float4(0.f, 0.f, 0.f, 0.f);
}

// ---------------------------------------------------------------------------
// One chunk = 8 steps, trapezoidal temporal blocking, 64x64 interior,
// 96x96 halo array, double-buffered LDS (1 barrier/step).
// Row validity is masked explicitly ([2+2s, 94-2s)); column garbage
// propagates inward exactly 2/step (16 total) and is absorbed by the
// 16-wide halo — interior [16,80) stays exact (same proof as round 3).
// ---------------------------------------------------------------------------
__global__ __launch_bounds__(NTHR, 3) void chunk_kernel(
    const float* __restrict__ x,       // (4,1,256,256)
    const float* __restrict__ se,      // (64,)
    float* __restrict__ out,           // (4,1,256,256) = [b][m][t]
    const float* __restrict__ gA,      // f_{n0}
    const float* __restrict__ gB,      // f_{n0-1}
    float* __restrict__ wA,            // f_{n0+K}
    float* __restrict__ wB,            // f_{n0+K-1}
    const int* __restrict__ tileTab,   // 64 tiles x 64 slots: d<<15|e<<8|m, -1 end
    const float* __restrict__ srcT,
    int n0)
{
    __shared__ __align__(16) float A0[WA * STR];
    __shared__ __align__(16) float A1[WA * STR];

    const int tid = threadIdx.x;
    const int blk = blockIdx.x;
    const int b   = blk >> 6;
    const int tb  = blk & 63;
    const int gi0 = (tb >> 3) << 6;
    const int gj0 = (tb & 7) << 6;
    const int bi0 = gi0 - 16;
    const int bj0 = gj0 - 16;

    const int rb = tid / 24;
    const int cb = tid - rb * 24;
    const int r0 = rb << 2;
    const int c0 = cb << 2;

    // ---- fill A0 with f_{n0}: 4 float4 per thread, coalesced ----
    const float* gAb = gA + (b << 18);
#pragma unroll
    for (int q = 0; q < 4; ++q) {
        int l   = tid + q * NTHR;      // 0..2303
        int li  = l / 24;              // row 0..95
        int lj4 = (l - li * 24) << 2;  // col 0,4,..,92
        int gi  = (bi0 + li) & 511;
        int gj  = (bj0 + lj4) & 511;
        *(float4*)&A0[li * STR + lj4] = *(const float4*)&gAb[(gi << 9) | gj];
    }

    // ---- per-thread register state ----
    float curR[4][4], prvR[4][4], v2R[4][4];
    const float* gBb = gB + (b << 18);
#pragma unroll
    for (int r = 0; r < 4; ++r) {
        int gi = (bi0 + r0 + r) & 511;
        int gjb = (bj0 + c0) & 511;
        float4 pv = *(const float4*)&gBb[(gi << 9) | gjb];
        prvR[r][0] = pv.x; prvR[r][1] = pv.y; prvR[r][2] = pv.z; prvR[r][3] = pv.w;
#pragma unroll
        for (int c = 0; c < 4; ++c) {
            int gj = gjb + c;
            float v;
            if (gi < 55 || gi >= 457 || gj < 55 || gj >= 457) v = 1e-6f;
            else if (gi >= 128 && gi < 384 && gj >= 128 && gj < 384)
                v = x[(b << 16) | ((gi - 128) << 8) | (gj - 128)];
            else v = 1.5f;
            float a = (2e-05f * v) / 1e-04f;
            v2R[r][c] = a * a;
        }
    }

    // ---- injection / measurement ownership (d:7b @15, e:7b @8, m:8b @0) ----
    int injCell = -1;  float injVal = 0.0f;
    int m1Cell = -1, m1Addr = 0, m2Cell = -1, m2Addr = 0;
    {
        const int* tt = tileTab + (tb << 6);
        for (int slot = 0; slot < TSLOTS; ++slot) {
            int pk = tt[slot];
            if (pk < 0) break;
            int d = pk >> 15, e = (pk >> 8) & 127, m = pk & 255;
            int lr = d - r0, lc = e - c0;
            if (lr < 0 || lr >= 4 || lc < 0 || lc >= 4) continue;
            int cell = (lr << 2) | lc;
            if ((m & 3) == 0) { injCell = cell; injVal = 0.09f * se[m >> 2]; }
            if (d >= 16 && d < 80 && e >= 16 && e < 80) {
                int addr = (b << 16) | (m << 8);
                if (m1Cell < 0) { m1Cell = cell; m1Addr = addr; }
                else            { m2Cell = cell; m2Addr = addr; }
            }
        }
    }

    __syncthreads();

    // own cur cells
#pragma unroll
    for (int r = 0; r < 4; ++r) {
        float4 t = *(const float4*)&A0[(r0 + r) * STR + c0];
        curR[r][0] = t.x; curR[r][1] = t.y; curR[r][2] = t.z; curR[r][3] = t.w;
    }

    for (int s = 0; s < K; ++s) {
        const float* Ac = (s & 1) ? A1 : A0;   // field n0+s
        float*       An = (s & 1) ? A0 : A1;
        const int lo = 2 + 2 * s;
        const int hi = WA - lo;
        const int n  = n0 + s;
        const float sv = srcT[n];

        bool rowAct[4];
#pragma unroll
        for (int r = 0; r < 4; ++r) {
            int ar = r0 + r;
            rowAct[r] = (ar >= lo) && (ar < hi);
        }

        // x-direction halo rows (rows outside own 4x4)
        float hxa[4], hxb[4], hxc[4], hxd[4];
        if (rowAct[0]) {
            float4 t = *(const float4*)&Ac[(r0 - 2) * STR + c0];
            hxa[0]=t.x; hxa[1]=t.y; hxa[2]=t.z; hxa[3]=t.w;
        }
        if (rowAct[0] || rowAct[1]) {
            float4 t = *(const float4*)&Ac[(r0 - 1) * STR + c0];
            hxb[0]=t.x; hxb[1]=t.y; hxb[2]=t.z; hxb[3]=t.w;
        }
        if (rowAct[2] || rowAct[3]) {
            float4 t = *(const float4*)&Ac[(r0 + 4) * STR + c0];
            hxc[0]=t.x; hxc[1]=t.y; hxc[2]=t.z; hxc[3]=t.w;
        }
        if (rowAct[3]) {
            float4 t = *(const float4*)&Ac[(r0 + 5) * STR + c0];
            hxd[0]=t.x; hxd[1]=t.y; hxd[2]=t.z; hxd[3]=t.w;
        }
        // y-direction halo (2 cols each side)
        float yl[4][2], yr[4][2];
#pragma unroll
        for (int r = 0; r < 4; ++r) {
            if (rowAct[r]) {
                int ar = r0 + r;
                float2 t1 = *(const float2*)&Ac[ar * STR + c0 - 2];
                float2 t2 = *(const float2*)&Ac[ar * STR + c0 + 4];
                yl[r][0] = t1.x; yl[r][1] = t1.y;
                yr[r][0] = t2.x; yr[r][1] = t2.y;
            }
        }

        float newR[4][4];
#pragma unroll
        for (int r = 0; r < 4; ++r) {
            if (!rowAct[r]) continue;
            float xm2_[4], xm1_[4], xp1_[4], xp2_[4];
#pragma unroll
            for (int c = 0; c < 4; ++c) {
                xm2_[c] = (r == 0) ? hxa[c] : (r == 1) ? hxb[c]
                                            : curR[(r >= 2) ? r - 2 : 0][c];
                xm1_[c] = (r == 0) ? hxb[c] : curR[(r >= 1) ? r - 1 : 0][c];
                xp1_[c] = (r < 3) ? curR[(r < 3) ? r + 1 : 3][c] : hxc[c];
                xp2_[c] = (r < 2) ? curR[(r < 2) ? r + 2 : 3][c]
                                  : ((r == 2) ? hxc[c] : hxd[c]);
            }
            float y[8] = {yl[r][0], yl[r][1],
                          curR[r][0], curR[r][1], curR[r][2], curR[r][3],
                          yr[r][0], yr[r][1]};
#pragma unroll
            for (int c = 0; c < 4; ++c) {
                float cc = curR[r][c];
                float nx = (-xm2_[c] + 16.0f * xm1_[c] - 30.0f * cc
                            + 16.0f * xp1_[c] - xp2_[c]) * (1.0f / 12.0f);
                float ny = (-y[c] + 16.0f * y[c + 1] - 30.0f * y[c + 2]
                            + 16.0f * y[c + 3] - y[c + 4]) * (1.0f / 12.0f);
                float p = 2.0f * cc - prvR[r][c] + v2R[r][c] * (nx + ny);
                int cell = (r << 2) | c;
                if (cell == injCell) p += injVal * sv;
                if (cell == m1Cell) out[m1Addr | n] = p;
                if (cell == m2Cell) out[m2Addr | n] = p;
                newR[r][c] = p;
            }
        }

        // write new field to the OTHER buffer; rotate registers
#pragma unroll
        for (int r = 0; r < 4; ++r) {
            if (!rowAct[r]) continue;
            *(float4*)&An[(r0 + r) * STR + c0] =
                make_float4(newR[r][0], newR[r][1], newR[r][2], newR[r][3]);
#pragma unroll
            for (int c = 0; c < 4; ++c) {
                prvR[r][c] = curR[r][c];
                curR[r][c] = newR[r][c];
            }
        }

        // last two fields -> global (interior only)
        if (s >= K - 2 && r0 >= 16 && r0 < 80 && c0 >= 16 && c0 < 80) {
            float* dst = (s == K - 2) ? wB : wA;
            int gj = gj0 + (c0 - 16);
#pragma unroll
            for (int r = 0; r < 4; ++r) {
                int gi = gi0 + (r0 - 16) + r;
                *(float4*)&dst[(b << 18) | (gi << 9) | gj] =
                    make_float4(curR[r][0], curR[r][1], curR[r][2], curR[r][3]);
            }
        }

        __syncthreads();   // An complete before next step reads it
    }
}

// ---------------------------------------------------------------------------
extern "C" void kernel_launch(void* const* d_in, const int* in_sizes, int n_in,
                              void* d_out, int out_size, void* d_ws, size_t ws_size,
                              hipStream_t stream) {
    const float* x  = (const float*)d_in[0];
    const float* se = (const float*)d_in[1];
    float* out = (float*)d_out;

    float* ws = (float*)d_ws;
    const int FSZ = NB * NPTS;                 // 4 MB per field (floats)
    float* f[4] = {ws, ws + FSZ, ws + 2 * FSZ, ws + 3 * FSZ};
    int*   dTab = (int*)(ws + 4 * FSZ);
    float* dSrc = (float*)(ws + 4 * FSZ + NTILES * TSLOTS);

    static int   h_tab[NTILES * TSLOTS];
    static float h_src[NT];
    static int   h_mx[NM], h_my[NM];
    for (int m = 0; m < NM; ++m) {
        double theta = (2.0 * M_PI * (double)m) / 256.0;
        h_mx[m] = (int)(256.0 + 200.0 * cos(theta));
        h_my[m] = (int)(256.0 + 200.0 * sin(theta));
    }
    for (int tile = 0; tile < NTILES; ++tile) {
        int bi0 = ((tile >> 3) << 6) - 16;
        int bj0 = ((tile & 7) << 6) - 16;
        int cnt = 0;
        for (int m = 0; m < NM; ++m) {
            int d = (h_mx[m] - bi0) & 511;
            int e = (h_my[m] - bj0) & 511;
            if (d < WA && e < WA && cnt < TSLOTS - 1)
                h_tab[tile * TSLOTS + cnt++] = (d << 15) | (e << 8) | m;  // 7b e!
        }
        for (; cnt < TSLOTS; ++cnt) h_tab[tile * TSLOTS + cnt] = -1;
    }
    for (int t = 0; t < NT; ++t) {
        float tj  = (float)t * 2e-05f;
        float arg = (float)(2.0 * M_PI * 500.0) * tj;
        float d   = tj - 0.002f;
        float e   = -(d * d) / (float)(2.0 * 0.001 * 0.001);
        h_src[t]  = sinf(arg) * expf(e);
    }
    hipMemcpyAsync(dTab, h_tab, sizeof(h_tab), hipMemcpyHostToDevice, stream);
    hipMemcpyAsync(dSrc, h_src, sizeof(h_src), hipMemcpyHostToDevice, stream);

    // zero chunk-0 input pair (f0A,f0B contiguous = 8 MB = 524288 float4)
    zero_kernel<<<2048, 256, 0, stream>>>((float4*)ws);

    for (int c = 0; c < NCH; ++c) {
        int p = c & 1, q = p ^ 1;
        chunk_kernel<<<NB * NTILES, NTHR, 0, stream>>>(
            x, se, out,
            f[2 * p], f[2 * p + 1],
            f[2 * q], f[2 * q + 1],
            dTab, dSrc, c * K);
    }
}

// Round 6
// 915.087 us; speedup vs baseline: 33.5137x; 1.0723x over previous
//
#include <hip/hip_runtime.h>
#include <math.h>

#define NXG 512
#define NPTS (NXG * NXG)
#define NB 4
#define NT 256
#define NM 256
#define K 16                // steps per chunk
#define NCH (NT / K)        // 16 chunks
#define TILE 64             // interior tile written back per chunk
#define WA 128              // halo-extended array (TILE + 2*2*K)
#define STR 132             // LDS row stride
#define NTHR 1024           // 32x32 thread grid, each owns 4x4 cells
#define NTILES 64           // 8x8 tiles cover 512x512

// ---------------------------------------------------------------------------
__global__ __launch_bounds__(256) void zero_kernel(float4* __restrict__ p) {
    p[blockIdx.x * 256 + threadIdx.x] = make_float4(0.f, 0.f, 0.f, 0.f);
}

// ---------------------------------------------------------------------------
// One chunk = 16 steps, trapezoidal temporal blocking, 64x64 interior,
// 128x128 halo array, double-buffered LDS (1 barrier/step).
// Row validity masked ([2+2s, 126-2s)); column garbage propagates 2/step
// (32 total) and is absorbed by the 32-wide halo — interior [32,96) exact.
// Per-(tile,thread) inj/meas resolved via ONE int2 load (host-precomputed).
// ---------------------------------------------------------------------------
__global__ __launch_bounds__(NTHR) void chunk_kernel(
    const float* __restrict__ x,       // (4,1,256,256)
    const float* __restrict__ se,      // (64,)
    float* __restrict__ out,           // (4,1,256,256) = [b][m][t]
    const float* __restrict__ gA,      // f_{n0}
    const float* __restrict__ gB,      // f_{n0-1}
    float* __restrict__ wA,            // f_{n0+K}
    float* __restrict__ wB,            // f_{n0+K-1}
    const int2* __restrict__ thrTab,   // 64 tiles x 1024 threads
    const float* __restrict__ srcT,
    int n0)
{
    __shared__ __align__(16) float A0[WA * STR];
    __shared__ __align__(16) float A1[WA * STR];

    const int tid = threadIdx.x;
    const int blk = blockIdx.x;
    const int b   = blk >> 6;
    const int tb  = blk & 63;
    const int gi0 = (tb >> 3) << 6;
    const int gj0 = (tb & 7) << 6;
    const int bi0 = gi0 - 32;
    const int bj0 = gj0 - 32;

    const int r0 = (tid >> 5) << 2;    // own rows r0..r0+3
    const int c0 = (tid & 31) << 2;    // own cols c0..c0+3

    // ---- fill A0 with f_{n0}: 4 float4 per thread, coalesced ----
    const float* gAb = gA + (b << 18);
#pragma unroll
    for (int q = 0; q < 4; ++q) {
        int l   = tid + q * NTHR;      // 0..4095
        int li  = l >> 5;              // row 0..127
        int lj4 = (l & 31) << 2;       // col 0,4,..,124
        int gi  = (bi0 + li) & 511;
        int gj  = (bj0 + lj4) & 511;   // bj0 mult of 32 -> float4 safe
        *(float4*)&A0[li * STR + lj4] = *(const float4*)&gAb[(gi << 9) | gj];
    }

    // ---- per-thread register state ----
    float curR[4][4], prvR[4][4], v2R[4][4];
    const float* gBb = gB + (b << 18);
#pragma unroll
    for (int r = 0; r < 4; ++r) {
        int gi  = (bi0 + r0 + r) & 511;
        int gjb = (bj0 + c0) & 511;
        float4 pv = *(const float4*)&gBb[(gi << 9) | gjb];
        prvR[r][0] = pv.x; prvR[r][1] = pv.y; prvR[r][2] = pv.z; prvR[r][3] = pv.w;
#pragma unroll
        for (int c = 0; c < 4; ++c) {
            int gj = gjb + c;
            float v;
            if (gi < 55 || gi >= 457 || gj < 55 || gj >= 457) v = 1e-6f;
            else if (gi >= 128 && gi < 384 && gj >= 128 && gj < 384)
                v = x[(b << 16) | ((gi - 128) << 8) | (gj - 128)];
            else v = 1.5f;
            float a = (2e-05f * v) / 1e-04f;
            v2R[r][c] = a * a;
        }
    }

    // ---- inj/meas: ONE int2 load per thread ----
    // tw.x: -1 or (seIdx<<8)|cell ; tw.y: two 16b halves 0x8000|(cell<<8)|m
    const int2 tw = thrTab[(tb << 10) | tid];
    int injCell = -1;  float injV = 0.0f;
    if (tw.x >= 0) { injCell = tw.x & 15; injV = 0.09f * se[tw.x >> 8]; }
    int m1Cell = -1, m1Addr = 0, m2Cell = -1, m2Addr = 0;
    {
        int h1 = tw.y & 0xFFFF, h2 = (tw.y >> 16) & 0xFFFF;
        if (h1 & 0x8000) { m1Cell = (h1 >> 8) & 15; m1Addr = (b << 16) | ((h1 & 255) << 8); }
        if (h2 & 0x8000) { m2Cell = (h2 >> 8) & 15; m2Addr = (b << 16) | ((h2 & 255) << 8); }
    }

    __syncthreads();

    // own cur cells
#pragma unroll
    for (int r = 0; r < 4; ++r) {
        float4 t = *(const float4*)&A0[(r0 + r) * STR + c0];
        curR[r][0] = t.x; curR[r][1] = t.y; curR[r][2] = t.z; curR[r][3] = t.w;
    }

    for (int s = 0; s < K; ++s) {
        const float* Ac = (s & 1) ? A1 : A0;   // field n0+s
        float*       An = (s & 1) ? A0 : A1;
        const int lo = 2 + 2 * s;
        const int hi = WA - lo;
        const int n  = n0 + s;
        const float sv = srcT[n];

        bool rowAct[4];
#pragma unroll
        for (int r = 0; r < 4; ++r) {
            int ar = r0 + r;
            rowAct[r] = (ar >= lo) && (ar < hi);
        }

        // x-direction halo rows (rows outside own 4x4)
        float hxa[4], hxb[4], hxc[4], hxd[4];
        if (rowAct[0]) {
            float4 t = *(const float4*)&Ac[(r0 - 2) * STR + c0];
            hxa[0]=t.x; hxa[1]=t.y; hxa[2]=t.z; hxa[3]=t.w;
        }
        if (rowAct[0] || rowAct[1]) {
            float4 t = *(const float4*)&Ac[(r0 - 1) * STR + c0];
            hxb[0]=t.x; hxb[1]=t.y; hxb[2]=t.z; hxb[3]=t.w;
        }
        if (rowAct[2] || rowAct[3]) {
            float4 t = *(const float4*)&Ac[(r0 + 4) * STR + c0];
            hxc[0]=t.x; hxc[1]=t.y; hxc[2]=t.z; hxc[3]=t.w;
        }
        if (rowAct[3]) {
            float4 t = *(const float4*)&Ac[(r0 + 5) * STR + c0];
            hxd[0]=t.x; hxd[1]=t.y; hxd[2]=t.z; hxd[3]=t.w;
        }
        // y-direction halo (2 cols each side)
        float yl[4][2], yr[4][2];
#pragma unroll
        for (int r = 0; r < 4; ++r) {
            if (rowAct[r]) {
                int ar = r0 + r;
                float2 t1 = *(const float2*)&Ac[ar * STR + c0 - 2];
                float2 t2 = *(const float2*)&Ac[ar * STR + c0 + 4];
                yl[r][0] = t1.x; yl[r][1] = t1.y;
                yr[r][0] = t2.x; yr[r][1] = t2.y;
            }
        }

        float newR[4][4];
#pragma unroll
        for (int r = 0; r < 4; ++r) {
            if (!rowAct[r]) continue;
            float xm2_[4], xm1_[4], xp1_[4], xp2_[4];
#pragma unroll
            for (int c = 0; c < 4; ++c) {
                xm2_[c] = (r == 0) ? hxa[c] : (r == 1) ? hxb[c]
                                            : curR[(r >= 2) ? r - 2 : 0][c];
                xm1_[c] = (r == 0) ? hxb[c] : curR[(r >= 1) ? r - 1 : 0][c];
                xp1_[c] = (r < 3) ? curR[(r < 3) ? r + 1 : 3][c] : hxc[c];
                xp2_[c] = (r < 2) ? curR[(r < 2) ? r + 2 : 3][c]
                                  : ((r == 2) ? hxc[c] : hxd[c]);
            }
            float y[8] = {yl[r][0], yl[r][1],
                          curR[r][0], curR[r][1], curR[r][2], curR[r][3],
                          yr[r][0], yr[r][1]};
#pragma unroll
            for (int c = 0; c < 4; ++c) {
                float cc = curR[r][c];
                // (16*sum1 - sum2 - 60*c)/12  == nab_x + nab_y
                float sum1 = (xm1_[c] + xp1_[c]) + (y[c + 1] + y[c + 3]);
                float sum2 = (xm2_[c] + xp2_[c]) + (y[c] + y[c + 4]);
                float w  = fmaf(-60.0f, cc, fmaf(16.0f, sum1, -sum2));
                newR[r][c] = fmaf(v2R[r][c], w * (1.0f / 12.0f),
                                  fmaf(2.0f, cc, -prvR[r][c]));
            }
        }

        // rare-wave branches: injection then measurement (post-injection value)
        if (injCell >= 0) {
            float add = injV * sv;
#pragma unroll
            for (int r = 0; r < 4; ++r)
#pragma unroll
                for (int c = 0; c < 4; ++c)
                    if (rowAct[r] && ((r << 2) | c) == injCell) newR[r][c] += add;
        }
        if (m1Cell >= 0) {
            float v = 0.0f;
#pragma unroll
            for (int r = 0; r < 4; ++r)
#pragma unroll
                for (int c = 0; c < 4; ++c)
                    if (((r << 2) | c) == m1Cell) v = newR[r][c];
            out[m1Addr | n] = v;
        }
        if (m2Cell >= 0) {
            float v = 0.0f;
#pragma unroll
            for (int r = 0; r < 4; ++r)
#pragma unroll
                for (int c = 0; c < 4; ++c)
                    if (((r << 2) | c) == m2Cell) v = newR[r][c];
            out[m2Addr | n] = v;
        }

        // write new field to the OTHER buffer; rotate registers
#pragma unroll
        for (int r = 0; r < 4; ++r) {
            if (!rowAct[r]) continue;
            *(float4*)&An[(r0 + r) * STR + c0] =
                make_float4(newR[r][0], newR[r][1], newR[r][2], newR[r][3]);
#pragma unroll
            for (int c = 0; c < 4; ++c) {
                prvR[r][c] = curR[r][c];
                curR[r][c] = newR[r][c];
            }
        }

        // last two fields -> global (interior only)
        if (s >= K - 2 && r0 >= 32 && r0 < 96 && c0 >= 32 && c0 < 96) {
            float* dst = (s == K - 2) ? wB : wA;
            int gj = gj0 + (c0 - 32);
#pragma unroll
            for (int r = 0; r < 4; ++r) {
                int gi = gi0 + (r0 - 32) + r;
                *(float4*)&dst[(b << 18) | (gi << 9) | gj] =
                    make_float4(curR[r][0], curR[r][1], curR[r][2], curR[r][3]);
            }
        }

        __syncthreads();   // An complete before next step reads it
    }
}

// ---------------------------------------------------------------------------
extern "C" void kernel_launch(void* const* d_in, const int* in_sizes, int n_in,
                              void* d_out, int out_size, void* d_ws, size_t ws_size,
                              hipStream_t stream) {
    const float* x  = (const float*)d_in[0];
    const float* se = (const float*)d_in[1];
    float* out = (float*)d_out;

    float* ws = (float*)d_ws;
    const int FSZ = NB * NPTS;                 // 4 MB per field (floats)
    float* f[4] = {ws, ws + FSZ, ws + 2 * FSZ, ws + 3 * FSZ};
    int2*  dTT  = (int2*)(ws + 4 * FSZ);                 // 64*1024 int2 = 512KB
    float* dSrc = (float*)(ws + 4 * FSZ + NTILES * NTHR * 2);

    static int   h_tt[NTILES * NTHR * 2];
    static float h_src[NT];
    static int   h_mx[NM], h_my[NM];
    for (int m = 0; m < NM; ++m) {
        double theta = (2.0 * M_PI * (double)m) / 256.0;
        h_mx[m] = (int)(256.0 + 200.0 * cos(theta));
        h_my[m] = (int)(256.0 + 200.0 * sin(theta));
    }
    for (int i = 0; i < NTILES * NTHR; ++i) { h_tt[2*i] = -1; h_tt[2*i+1] = 0; }
    for (int tile = 0; tile < NTILES; ++tile) {
        int bi0 = ((tile >> 3) << 6) - 32;
        int bj0 = ((tile & 7) << 6) - 32;
        for (int m = 0; m < NM; ++m) {
            int d = (h_mx[m] - bi0) & 511;
            int e = (h_my[m] - bj0) & 511;
            if (d >= WA || e >= WA) continue;
            int tidx = (d >> 2) * 32 + (e >> 2);
            int cell = ((d & 3) << 2) | (e & 3);
            int base = (tile * NTHR + tidx) * 2;
            if ((m & 3) == 0) h_tt[base] = ((m >> 2) << 8) | cell;
            if (d >= 32 && d < 96 && e >= 32 && e < 96) {
                int half = 0x8000 | (cell << 8) | m;
                if (!(h_tt[base + 1] & 0x8000)) h_tt[base + 1] |= half;
                else                            h_tt[base + 1] |= half << 16;
            }
        }
    }
    for (int t = 0; t < NT; ++t) {
        float tj  = (float)t * 2e-05f;
        float arg = (float)(2.0 * M_PI * 500.0) * tj;
        float d   = tj - 0.002f;
        float e   = -(d * d) / (float)(2.0 * 0.001 * 0.001);
        h_src[t]  = sinf(arg) * expf(e);
    }
    hipMemcpyAsync(dTT,  h_tt,  sizeof(h_tt),  hipMemcpyHostToDevice, stream);
    hipMemcpyAsync(dSrc, h_src, sizeof(h_src), hipMemcpyHostToDevice, stream);

    // zero chunk-0 input pair (f0A,f0B contiguous = 8 MB = 524288 float4)
    zero_kernel<<<2048, 256, 0, stream>>>((float4*)ws);

    for (int c = 0; c < NCH; ++c) {
        int p = c & 1, q = p ^ 1;
        chunk_kernel<<<NB * NTILES, NTHR, 0, stream>>>(
            x, se, out,
            f[2 * p], f[2 * p + 1],
            f[2 * q], f[2 * q + 1],
            dTT, dSrc, c * K);
    }
}

// Round 7
// 799.216 us; speedup vs baseline: 38.3725x; 1.1450x over previous
//
#include <hip/hip_runtime.h>
#include <math.h>

#define NXG 512
#define NPTS (NXG * NXG)
#define NB 4
#define NT 256
#define NM 256
#define K 16                // steps per chunk
#define NCH (NT / K)        // 16 chunks
#define WA 128              // halo-extended logical array (64 + 2*2*K)
#define STR 132             // LDS row stride (floats); also right col pad
#define PROWS (WA + 4)      // physical rows: logical -2..129
#define NTHR 1024           // 32x32 thread grid, each owns 4x4 cells
#define NTILES 64           // 8x8 tiles cover 512x512

// ---------------------------------------------------------------------------
__global__ __launch_bounds__(256) void zero_kernel(float4* __restrict__ p) {
    p[blockIdx.x * 256 + threadIdx.x] = make_float4(0.f, 0.f, 0.f, 0.f);
}

// ---------------------------------------------------------------------------
// One step for one thread's 4x4 block. Reads cur[][]+prv[][]+LDS halo of Ac,
// writes the new field INTO prv (caller swaps roles next step — no movs),
// stores the 4 rows to An, applies injection, writes measurements.
// Completely unmasked: row/col garbage propagates 2/step and is absorbed
// by the 32-wide halo (interior [32,96) exact at s=15).
// ---------------------------------------------------------------------------
__device__ __forceinline__ void do_step(
    const float* __restrict__ Ac, float* __restrict__ An,
    float* __restrict__ out,
    const float (&v2R)[4][4], float (&cur)[4][4], float (&prv)[4][4],
    int r0, int c0, int injCell, float add,
    int m1Cell, int m1Addr, int m2Cell, int m2Addr, int n)
{
    // x-halo rows (b128, canonical conflict-free)
    float4 hxa = *(const float4*)&Ac[(r0 - 2) * STR + c0];
    float4 hxb = *(const float4*)&Ac[(r0 - 1) * STR + c0];
    float4 hxc = *(const float4*)&Ac[(r0 + 4) * STR + c0];
    float4 hxd = *(const float4*)&Ac[(r0 + 5) * STR + c0];
    // y-halo: aligned b128 each side (use .z/.w of left, .x/.y of right)
    float4 yl[4], yr[4];
#pragma unroll
    for (int r = 0; r < 4; ++r) {
        yl[r] = *(const float4*)&Ac[(r0 + r) * STR + c0 - 4];
        yr[r] = *(const float4*)&Ac[(r0 + r) * STR + c0 + 4];
    }

    float ha[4] = {hxa.x, hxa.y, hxa.z, hxa.w};
    float hb[4] = {hxb.x, hxb.y, hxb.z, hxb.w};
    float hc[4] = {hxc.x, hxc.y, hxc.z, hxc.w};
    float hd[4] = {hxd.x, hxd.y, hxd.z, hxd.w};

#pragma unroll
    for (int r = 0; r < 4; ++r) {
        float y[8] = {yl[r].z, yl[r].w,
                      cur[r][0], cur[r][1], cur[r][2], cur[r][3],
                      yr[r].x, yr[r].y};
        float pn[4];
#pragma unroll
        for (int c = 0; c < 4; ++c) {
            float xm2 = (r == 0) ? ha[c] : (r == 1) ? hb[c] : cur[r - 2][c];
            float xm1 = (r == 0) ? hb[c] : cur[r - 1][c];
            float xp1 = (r == 3) ? hc[c] : cur[r + 1][c];
            float xp2 = (r == 2) ? hc[c] : (r == 3) ? hd[c] : cur[r + 2][c];
            float cc  = cur[r][c];
            float sum1 = (xm1 + xp1) + (y[c + 1] + y[c + 3]);
            float sum2 = (xm2 + xp2) + (y[c] + y[c + 4]);
            float w = fmaf(-60.0f, cc, fmaf(16.0f, sum1, -sum2));
            float p = fmaf(v2R[r][c], w * (1.0f / 12.0f),
                           fmaf(2.0f, cc, -prv[r][c]));
            if (((r << 2) | c) == injCell) p += add;
            pn[c] = p;
        }
        if (m1Cell >= 0 && (m1Cell >> 2) == r) out[m1Addr | n] = pn[m1Cell & 3];
        if (m2Cell >= 0 && (m2Cell >> 2) == r) out[m2Addr | n] = pn[m2Cell & 3];
        *(float4*)&An[(r0 + r) * STR + c0] =
            make_float4(pn[0], pn[1], pn[2], pn[3]);
        prv[r][0] = pn[0]; prv[r][1] = pn[1]; prv[r][2] = pn[2]; prv[r][3] = pn[3];
    }
}

// ---------------------------------------------------------------------------
__global__ __launch_bounds__(NTHR, 4) void chunk_kernel(
    const float* __restrict__ x,       // (4,1,256,256)
    const float* __restrict__ se,      // (64,)
    float* __restrict__ out,           // (4,1,256,256) = [b][m][t]
    const float* __restrict__ gA,      // f_{n0}
    const float* __restrict__ gB,      // f_{n0-1}
    float* __restrict__ wA,            // f_{n0+K}
    float* __restrict__ wB,            // f_{n0+K-1}
    const int2* __restrict__ thrTab,   // 64 tiles x 1024 threads
    const float* __restrict__ srcT,
    int n0)
{
    __shared__ __align__(16) float S0[PROWS * STR];
    __shared__ __align__(16) float S1[PROWS * STR];
    float* A0 = S0 + 2 * STR;          // logical row 0
    float* A1 = S1 + 2 * STR;

    const int tid = threadIdx.x;
    const int blk = blockIdx.x;
    const int b   = blk >> 6;
    const int tb  = blk & 63;
    const int gi0 = (tb >> 3) << 6;
    const int gj0 = (tb & 7) << 6;
    const int bi0 = gi0 - 32;
    const int bj0 = gj0 - 32;

    const int r0 = (tid >> 5) << 2;    // own rows r0..r0+3 (logical)
    const int c0 = (tid & 31) << 2;

    // ---- zero pad rows of both buffers (8 rows x 33 b128 = 264 stores) ----
    if (tid < 264) {
        int buf = tid >= 132;
        int q   = tid - (buf ? 132 : 0);   // 0..131
        int pr  = q / 33;                  // pad row 0..3
        int pc  = (q - pr * 33) << 2;      // col 0,4,..,128
        int prow = (pr < 2) ? pr : (pr + WA);   // physical rows 0,1,130,131
        float* S = buf ? S1 : S0;
        // guard col 128..131 (STR=132 leaves exactly one extra b128 slot)
        *(float4*)&S[prow * STR + pc] = make_float4(0.f, 0.f, 0.f, 0.f);
    }

    // ---- fill A0 with f_{n0}: 4 float4 per thread, coalesced ----
    const float* gAb = gA + (b << 18);
#pragma unroll
    for (int q = 0; q < 4; ++q) {
        int l   = tid + q * NTHR;      // 0..4095
        int li  = l >> 5;              // logical row 0..127
        int lj4 = (l & 31) << 2;
        int gi  = (bi0 + li) & 511;
        int gj  = (bj0 + lj4) & 511;
        *(float4*)&A0[li * STR + lj4] = *(const float4*)&gAb[(gi << 9) | gj];
    }

    // ---- per-thread register state ----
    float curR[4][4], prvR[4][4], v2R[4][4];
    const float* gBb = gB + (b << 18);
#pragma unroll
    for (int r = 0; r < 4; ++r) {
        int gi  = (bi0 + r0 + r) & 511;
        int gjb = (bj0 + c0) & 511;
        float4 pv = *(const float4*)&gBb[(gi << 9) | gjb];
        prvR[r][0] = pv.x; prvR[r][1] = pv.y; prvR[r][2] = pv.z; prvR[r][3] = pv.w;
#pragma unroll
        for (int c = 0; c < 4; ++c) {
            int gj = gjb + c;
            float v;
            if (gi < 55 || gi >= 457 || gj < 55 || gj >= 457) v = 1e-6f;
            else if (gi >= 128 && gi < 384 && gj >= 128 && gj < 384)
                v = x[(b << 16) | ((gi - 128) << 8) | (gj - 128)];
            else v = 1.5f;
            float a = (2e-05f * v) / 1e-04f;
            v2R[r][c] = a * a;
        }
    }

    // ---- inj/meas: ONE int2 load per thread ----
    const int2 tw = thrTab[(tb << 10) | tid];
    int injCell = -1;  float injV = 0.0f;
    if (tw.x >= 0) { injCell = tw.x & 15; injV = 0.09f * se[tw.x >> 8]; }
    int m1Cell = -1, m1Addr = 0, m2Cell = -1, m2Addr = 0;
    {
        int h1 = tw.y & 0xFFFF, h2 = (tw.y >> 16) & 0xFFFF;
        if (h1 & 0x8000) { m1Cell = (h1 >> 8) & 15; m1Addr = (b << 16) | ((h1 & 255) << 8); }
        if (h2 & 0x8000) { m2Cell = (h2 >> 8) & 15; m2Addr = (b << 16) | ((h2 & 255) << 8); }
    }

    __syncthreads();

    // own cur cells
#pragma unroll
    for (int r = 0; r < 4; ++r) {
        float4 t = *(const float4*)&A0[(r0 + r) * STR + c0];
        curR[r][0] = t.x; curR[r][1] = t.y; curR[r][2] = t.z; curR[r][3] = t.w;
    }

    // K steps, 2 per iteration, register role swap (no rotation movs)
#pragma unroll 1
    for (int s = 0; s < K; s += 2) {
        int n = n0 + s;
        do_step(A0, A1, out, v2R, curR, prvR, r0, c0,
                injCell, injV * srcT[n], m1Cell, m1Addr, m2Cell, m2Addr, n);
        // prvR now holds field n+1 (cur), curR holds field n (prev)
        if (s == K - 2 && r0 >= 32 && r0 < 96 && c0 >= 32 && c0 < 96) {
            int gj = gj0 + (c0 - 32);
#pragma unroll
            for (int r = 0; r < 4; ++r) {
                int gi = gi0 + (r0 - 32) + r;
                *(float4*)&wB[(b << 18) | (gi << 9) | gj] =
                    make_float4(prvR[r][0], prvR[r][1], prvR[r][2], prvR[r][3]);
            }
        }
        __syncthreads();

        n = n0 + s + 1;
        do_step(A1, A0, out, v2R, prvR, curR, r0, c0,
                injCell, injV * srcT[n], m1Cell, m1Addr, m2Cell, m2Addr, n);
        // curR now holds field n+2
        if (s == K - 2 && r0 >= 32 && r0 < 96 && c0 >= 32 && c0 < 96) {
            int gj = gj0 + (c0 - 32);
#pragma unroll
            for (int r = 0; r < 4; ++r) {
                int gi = gi0 + (r0 - 32) + r;
                *(float4*)&wA[(b << 18) | (gi << 9) | gj] =
                    make_float4(curR[r][0], curR[r][1], curR[r][2], curR[r][3]);
            }
        }
        __syncthreads();
    }
}

// ---------------------------------------------------------------------------
extern "C" void kernel_launch(void* const* d_in, const int* in_sizes, int n_in,
                              void* d_out, int out_size, void* d_ws, size_t ws_size,
                              hipStream_t stream) {
    const float* x  = (const float*)d_in[0];
    const float* se = (const float*)d_in[1];
    float* out = (float*)d_out;

    float* ws = (float*)d_ws;
    const int FSZ = NB * NPTS;                 // 4 MB per field (floats)
    float* f[4] = {ws, ws + FSZ, ws + 2 * FSZ, ws + 3 * FSZ};
    int2*  dTT  = (int2*)(ws + 4 * FSZ);
    float* dSrc = (float*)(ws + 4 * FSZ + NTILES * NTHR * 2);

    static int   h_tt[NTILES * NTHR * 2];
    static float h_src[NT];
    static int   h_mx[NM], h_my[NM];
    for (int m = 0; m < NM; ++m) {
        double theta = (2.0 * M_PI * (double)m) / 256.0;
        h_mx[m] = (int)(256.0 + 200.0 * cos(theta));
        h_my[m] = (int)(256.0 + 200.0 * sin(theta));
    }
    for (int i = 0; i < NTILES * NTHR; ++i) { h_tt[2*i] = -1; h_tt[2*i+1] = 0; }
    for (int tile = 0; tile < NTILES; ++tile) {
        int bi0 = ((tile >> 3) << 6) - 32;
        int bj0 = ((tile & 7) << 6) - 32;
        for (int m = 0; m < NM; ++m) {
            int d = (h_mx[m] - bi0) & 511;
            int e = (h_my[m] - bj0) & 511;
            if (d >= WA || e >= WA) continue;
            int tidx = (d >> 2) * 32 + (e >> 2);
            int cell = ((d & 3) << 2) | (e & 3);
            int base = (tile * NTHR + tidx) * 2;
            if ((m & 3) == 0) h_tt[base] = ((m >> 2) << 8) | cell;
            if (d >= 32 && d < 96 && e >= 32 && e < 96) {
                int half = 0x8000 | (cell << 8) | m;
                if (!(h_tt[base + 1] & 0x8000)) h_tt[base + 1] |= half;
                else                            h_tt[base + 1] |= half << 16;
            }
        }
    }
    for (int t = 0; t < NT; ++t) {
        float tj  = (float)t * 2e-05f;
        float arg = (float)(2.0 * M_PI * 500.0) * tj;
        float d   = tj - 0.002f;
        float e   = -(d * d) / (float)(2.0 * 0.001 * 0.001);
        h_src[t]  = sinf(arg) * expf(e);
    }
    hipMemcpyAsync(dTT,  h_tt,  sizeof(h_tt),  hipMemcpyHostToDevice, stream);
    hipMemcpyAsync(dSrc, h_src, sizeof(h_src), hipMemcpyHostToDevice, stream);

    // zero chunk-0 input pair (f0A,f0B contiguous = 8 MB = 524288 float4)
    zero_kernel<<<2048, 256, 0, stream>>>((float4*)ws);

    for (int c = 0; c < NCH; ++c) {
        int p = c & 1, q = p ^ 1;
        chunk_kernel<<<NB * NTILES, NTHR, 0, stream>>>(
            x, se, out,
            f[2 * p], f[2 * p + 1],
            f[2 * q], f[2 * q + 1],
            dTT, dSrc, c * K);
    }
}

// Round 8
// 756.700 us; speedup vs baseline: 40.5285x; 1.0562x over previous
//
#include <hip/hip_runtime.h>
#include <math.h>

#define NXG 512
#define NPTS (NXG * NXG)
#define NB 4
#define NT 256
#define NM 256
#define K 16                // steps per chunk
#define NCH (NT / K)        // 16 chunks
#define WA 128              // halo-extended logical array (64 + 2*2*K)
#define STR 132             // LDS row stride (floats)
#define PROWS (WA + 4)      // physical rows: logical -2..129
#define NTHR 1024           // 32x32 thread grid, each owns 4x4 cells
#define NTILES 64           // 8x8 tiles cover 512x512

// ---------------------------------------------------------------------------
__global__ __launch_bounds__(256) void zero_kernel(float4* __restrict__ p) {
    p[blockIdx.x * 256 + threadIdx.x] = make_float4(0.f, 0.f, 0.f, 0.f);
}

// DPP wave shifts: lane l <- lane l-1 (wave_shr1=0x138) / lane l+1 (0x130).
// Invalid lanes read 0 (bound_ctrl) — only edge threads (c0=0/124), whose
// cells are garbage-tolerant halo, ever receive shifted-in junk.
__device__ __forceinline__ float dpp_left(float v) {   // from lane-1
    return __int_as_float(__builtin_amdgcn_mov_dpp(__float_as_int(v),
                                                   0x138, 0xf, 0xf, true));
}
__device__ __forceinline__ float dpp_right(float v) {  // from lane+1
    return __int_as_float(__builtin_amdgcn_mov_dpp(__float_as_int(v),
                                                   0x130, 0xf, 0xf, true));
}

// ---------------------------------------------------------------------------
// One step for one thread's 4x4 block. x-halo from LDS (4 b128 reads),
// y-halo from lane+-1 registers via DPP (VALU pipe — no LDS traffic).
// Writes new field INTO prv (caller swaps roles), stores 4 rows to An.
// Unmasked: garbage propagates 2 cells/step, absorbed by 32-wide halo.
// ---------------------------------------------------------------------------
__device__ __forceinline__ void do_step(
    const float* __restrict__ Ac, float* __restrict__ An,
    float* __restrict__ out,
    const float (&v2R)[4][4], float (&cur)[4][4], float (&prv)[4][4],
    int r0, int c0, int injCell, float add,
    int m1Cell, int m1Addr, int m2Cell, int m2Addr, int n)
{
    // x-halo rows (b128, canonical conflict-free)
    float4 hxa = *(const float4*)&Ac[(r0 - 2) * STR + c0];
    float4 hxb = *(const float4*)&Ac[(r0 - 1) * STR + c0];
    float4 hxc = *(const float4*)&Ac[(r0 + 4) * STR + c0];
    float4 hxd = *(const float4*)&Ac[(r0 + 5) * STR + c0];

    float ha[4] = {hxa.x, hxa.y, hxa.z, hxa.w};
    float hb[4] = {hxb.x, hxb.y, hxb.z, hxb.w};
    float hc[4] = {hxc.x, hxc.y, hxc.z, hxc.w};
    float hd[4] = {hxd.x, hxd.y, hxd.z, hxd.w};

#pragma unroll
    for (int r = 0; r < 4; ++r) {
        // y-halo via DPP: cols c0-2,c0-1 = lane-1's cells 2,3;
        //                 cols c0+4,c0+5 = lane+1's cells 0,1.
        float y[8] = {dpp_left(cur[r][2]), dpp_left(cur[r][3]),
                      cur[r][0], cur[r][1], cur[r][2], cur[r][3],
                      dpp_right(cur[r][0]), dpp_right(cur[r][1])};
        float pn[4];
#pragma unroll
        for (int c = 0; c < 4; ++c) {
            float xm2 = (r == 0) ? ha[c] : (r == 1) ? hb[c] : cur[r - 2][c];
            float xm1 = (r == 0) ? hb[c] : cur[r - 1][c];
            float xp1 = (r == 3) ? hc[c] : cur[r + 1][c];
            float xp2 = (r == 2) ? hc[c] : (r == 3) ? hd[c] : cur[r + 2][c];
            float cc  = cur[r][c];
            float sum1 = (xm1 + xp1) + (y[c + 1] + y[c + 3]);
            float sum2 = (xm2 + xp2) + (y[c] + y[c + 4]);
            float w = fmaf(-60.0f, cc, fmaf(16.0f, sum1, -sum2));
            // v2R pre-divided by 12
            float p = fmaf(v2R[r][c], w, fmaf(2.0f, cc, -prv[r][c]));
            if (((r << 2) | c) == injCell) p += add;
            pn[c] = p;
        }
        if (m1Cell >= 0 && (m1Cell >> 2) == r) out[m1Addr | n] = pn[m1Cell & 3];
        if (m2Cell >= 0 && (m2Cell >> 2) == r) out[m2Addr | n] = pn[m2Cell & 3];
        *(float4*)&An[(r0 + r) * STR + c0] =
            make_float4(pn[0], pn[1], pn[2], pn[3]);
        prv[r][0] = pn[0]; prv[r][1] = pn[1]; prv[r][2] = pn[2]; prv[r][3] = pn[3];
    }
}

// ---------------------------------------------------------------------------
__global__ __launch_bounds__(NTHR, 4) void chunk_kernel(
    const float* __restrict__ x,       // (4,1,256,256)
    const float* __restrict__ se,      // (64,)
    float* __restrict__ out,           // (4,1,256,256) = [b][m][t]
    const float* __restrict__ gA,      // f_{n0}
    const float* __restrict__ gB,      // f_{n0-1}
    float* __restrict__ wA,            // f_{n0+K}
    float* __restrict__ wB,            // f_{n0+K-1}
    const int2* __restrict__ thrTab,   // 64 tiles x 1024 threads
    const float* __restrict__ srcT,
    int n0)
{
    __shared__ __align__(16) float S0[PROWS * STR];
    __shared__ __align__(16) float S1[PROWS * STR];
    float* A0 = S0 + 2 * STR;          // logical row 0
    float* A1 = S1 + 2 * STR;

    const int tid = threadIdx.x;
    const int blk = blockIdx.x;
    const int b   = blk >> 6;
    const int tb  = blk & 63;
    const int gi0 = (tb >> 3) << 6;
    const int gj0 = (tb & 7) << 6;
    const int bi0 = gi0 - 32;
    const int bj0 = gj0 - 32;

    const int r0 = (tid >> 5) << 2;    // own rows (logical)
    const int c0 = (tid & 31) << 2;

    // ---- zero pad rows of both buffers ----
    if (tid < 264) {
        int buf = tid >= 132;
        int q   = tid - (buf ? 132 : 0);
        int pr  = q / 33;
        int pc  = (q - pr * 33) << 2;
        int prow = (pr < 2) ? pr : (pr + WA);
        float* S = buf ? S1 : S0;
        *(float4*)&S[prow * STR + pc] = make_float4(0.f, 0.f, 0.f, 0.f);
    }

    // ---- fill A0 with f_{n0}: 4 float4 per thread, coalesced ----
    const float* gAb = gA + (b << 18);
#pragma unroll
    for (int q = 0; q < 4; ++q) {
        int l   = tid + q * NTHR;
        int li  = l >> 5;
        int lj4 = (l & 31) << 2;
        int gi  = (bi0 + li) & 511;
        int gj  = (bj0 + lj4) & 511;
        *(float4*)&A0[li * STR + lj4] = *(const float4*)&gAb[(gi << 9) | gj];
    }

    // ---- per-thread register state (v2R pre-divided by 12) ----
    float curR[4][4], prvR[4][4], v2R[4][4];
    const float* gBb = gB + (b << 18);
#pragma unroll
    for (int r = 0; r < 4; ++r) {
        int gi  = (bi0 + r0 + r) & 511;
        int gjb = (bj0 + c0) & 511;
        float4 pv = *(const float4*)&gBb[(gi << 9) | gjb];
        prvR[r][0] = pv.x; prvR[r][1] = pv.y; prvR[r][2] = pv.z; prvR[r][3] = pv.w;
#pragma unroll
        for (int c = 0; c < 4; ++c) {
            int gj = gjb + c;
            float v;
            if (gi < 55 || gi >= 457 || gj < 55 || gj >= 457) v = 1e-6f;
            else if (gi >= 128 && gi < 384 && gj >= 128 && gj < 384)
                v = x[(b << 16) | ((gi - 128) << 8) | (gj - 128)];
            else v = 1.5f;
            float a = (2e-05f * v) / 1e-04f;
            v2R[r][c] = a * a * (1.0f / 12.0f);
        }
    }

    // ---- inj/meas: ONE int2 load per thread ----
    const int2 tw = thrTab[(tb << 10) | tid];
    int injCell = -1;  float injV = 0.0f;
    if (tw.x >= 0) { injCell = tw.x & 15; injV = 0.09f * se[tw.x >> 8]; }
    int m1Cell = -1, m1Addr = 0, m2Cell = -1, m2Addr = 0;
    {
        int h1 = tw.y & 0xFFFF, h2 = (tw.y >> 16) & 0xFFFF;
        if (h1 & 0x8000) { m1Cell = (h1 >> 8) & 15; m1Addr = (b << 16) | ((h1 & 255) << 8); }
        if (h2 & 0x8000) { m2Cell = (h2 >> 8) & 15; m2Addr = (b << 16) | ((h2 & 255) << 8); }
    }

    __syncthreads();

    // own cur cells
#pragma unroll
    for (int r = 0; r < 4; ++r) {
        float4 t = *(const float4*)&A0[(r0 + r) * STR + c0];
        curR[r][0] = t.x; curR[r][1] = t.y; curR[r][2] = t.z; curR[r][3] = t.w;
    }

    // K steps, 2 per iteration, register role swap
#pragma unroll 1
    for (int s = 0; s < K; s += 2) {
        int n = n0 + s;
        do_step(A0, A1, out, v2R, curR, prvR, r0, c0,
                injCell, injV * srcT[n], m1Cell, m1Addr, m2Cell, m2Addr, n);
        if (s == K - 2 && r0 >= 32 && r0 < 96 && c0 >= 32 && c0 < 96) {
            int gj = gj0 + (c0 - 32);
#pragma unroll
            for (int r = 0; r < 4; ++r) {
                int gi = gi0 + (r0 - 32) + r;
                *(float4*)&wB[(b << 18) | (gi << 9) | gj] =
                    make_float4(prvR[r][0], prvR[r][1], prvR[r][2], prvR[r][3]);
            }
        }
        __syncthreads();

        n = n0 + s + 1;
        do_step(A1, A0, out, v2R, prvR, curR, r0, c0,
                injCell, injV * srcT[n], m1Cell, m1Addr, m2Cell, m2Addr, n);
        if (s == K - 2 && r0 >= 32 && r0 < 96 && c0 >= 32 && c0 < 96) {
            int gj = gj0 + (c0 - 32);
#pragma unroll
            for (int r = 0; r < 4; ++r) {
                int gi = gi0 + (r0 - 32) + r;
                *(float4*)&wA[(b << 18) | (gi << 9) | gj] =
                    make_float4(curR[r][0], curR[r][1], curR[r][2], curR[r][3]);
            }
        }
        __syncthreads();
    }
}

// ---------------------------------------------------------------------------
extern "C" void kernel_launch(void* const* d_in, const int* in_sizes, int n_in,
                              void* d_out, int out_size, void* d_ws, size_t ws_size,
                              hipStream_t stream) {
    const float* x  = (const float*)d_in[0];
    const float* se = (const float*)d_in[1];
    float* out = (float*)d_out;

    float* ws = (float*)d_ws;
    const int FSZ = NB * NPTS;                 // 4 MB per field (floats)
    float* f[4] = {ws, ws + FSZ, ws + 2 * FSZ, ws + 3 * FSZ};
    int2*  dTT  = (int2*)(ws + 4 * FSZ);
    float* dSrc = (float*)(ws + 4 * FSZ + NTILES * NTHR * 2);

    static int   h_tt[NTILES * NTHR * 2];
    static float h_src[NT];
    static int   h_mx[NM], h_my[NM];
    for (int m = 0; m < NM; ++m) {
        double theta = (2.0 * M_PI * (double)m) / 256.0;
        h_mx[m] = (int)(256.0 + 200.0 * cos(theta));
        h_my[m] = (int)(256.0 + 200.0 * sin(theta));
    }
    for (int i = 0; i < NTILES * NTHR; ++i) { h_tt[2*i] = -1; h_tt[2*i+1] = 0; }
    for (int tile = 0; tile < NTILES; ++tile) {
        int bi0 = ((tile >> 3) << 6) - 32;
        int bj0 = ((tile & 7) << 6) - 32;
        for (int m = 0; m < NM; ++m) {
            int d = (h_mx[m] - bi0) & 511;
            int e = (h_my[m] - bj0) & 511;
            if (d >= WA || e >= WA) continue;
            int tidx = (d >> 2) * 32 + (e >> 2);
            int cell = ((d & 3) << 2) | (e & 3);
            int base = (tile * NTHR + tidx) * 2;
            if ((m & 3) == 0) h_tt[base] = ((m >> 2) << 8) | cell;
            if (d >= 32 && d < 96 && e >= 32 && e < 96) {
                int half = 0x8000 | (cell << 8) | m;
                if (!(h_tt[base + 1] & 0x8000)) h_tt[base + 1] |= half;
                else                            h_tt[base + 1] |= half << 16;
            }
        }
    }
    for (int t = 0; t < NT; ++t) {
        float tj  = (float)t * 2e-05f;
        float arg = (float)(2.0 * M_PI * 500.0) * tj;
        float d   = tj - 0.002f;
        float e   = -(d * d) / (float)(2.0 * 0.001 * 0.001);
        h_src[t]  = sinf(arg) * expf(e);
    }
    hipMemcpyAsync(dTT,  h_tt,  sizeof(h_tt),  hipMemcpyHostToDevice, stream);
    hipMemcpyAsync(dSrc, h_src, sizeof(h_src), hipMemcpyHostToDevice, stream);

    // zero chunk-0 input pair (f0A,f0B contiguous = 8 MB = 524288 float4)
    zero_kernel<<<2048, 256, 0, stream>>>((float4*)ws);

    for (int c = 0; c < NCH; ++c) {
        int p = c & 1, q = p ^ 1;
        chunk_kernel<<<NB * NTILES, NTHR, 0, stream>>>(
            x, se, out,
            f[2 * p], f[2 * p + 1],
            f[2 * q], f[2 * q + 1],
            dTT, dSrc, c * K);
    }
}